// Round 4
// baseline (78.990 us; speedup 1.0000x reference)
//
#include <hip/hip_runtime.h>
#include <hip/hip_bf16.h>
#include <math.h>

#define N_NODES 2048
#define IN_F    1024
#define NH      8
#define HF      32
#define OUTF    256   // NH*HF
#define JSPLIT  4
#define JR      (N_NODES / JSPLIT)   // 512 j's per attention block
#define KSPLIT  4                    // K-split for the g GEMM

typedef __attribute__((ext_vector_type(8))) short short8;
typedef __attribute__((ext_vector_type(4))) float f32x4;

__device__ __forceinline__ short f2bf(float x) {   // fp32 -> bf16 bits, RNE
  unsigned u = __float_as_uint(x);
  return (short)((u + 0x7FFFu + ((u >> 16) & 1u)) >> 16);
}
__device__ __forceinline__ float bf2f(short b) {
  return __uint_as_float(((unsigned)(unsigned short)b) << 16);
}

// ---------------- Kernel 0a: split h into bf16 hi/lo -----------------------
__global__ __launch_bounds__(256)
void prep_h_kernel(const float* __restrict__ h, short* __restrict__ hhi,
                   short* __restrict__ hlo) {
  const int idx = blockIdx.x * 256 + threadIdx.x;   // 8 floats per thread
  const float4 v0 = *(const float4*)(h + idx * 8);
  const float4 v1 = *(const float4*)(h + idx * 8 + 4);
  const float x[8] = {v0.x, v0.y, v0.z, v0.w, v1.x, v1.y, v1.z, v1.w};
  short8 hi, lo;
  #pragma unroll
  for (int j = 0; j < 8; ++j) {
    const short hb = f2bf(x[j]);
    hi[j] = hb;
    lo[j] = f2bf(x[j] - bf2f(hb));
  }
  *(short8*)(hhi + idx * 8) = hi;
  *(short8*)(hlo + idx * 8) = lo;
}

// ---------------- Kernel 0b: split + transpose W -> Wt[n][k] bf16 hi/lo ----
__global__ __launch_bounds__(256)
void prep_w_kernel(const float* __restrict__ W, short* __restrict__ wthi,
                   short* __restrict__ wtlo) {
  const int idx = blockIdx.x * 256 + threadIdx.x;   // n*128 + kg
  const int n = idx >> 7, kg = idx & 127;
  short8 hi, lo;
  #pragma unroll
  for (int j = 0; j < 8; ++j) {
    const float x = W[(kg * 8 + j) * OUTF + n];
    const short hb = f2bf(x);
    hi[j] = hb;
    lo[j] = f2bf(x - bf2f(hb));
  }
  *(short8*)(wthi + n * IN_F + kg * 8) = hi;
  *(short8*)(wtlo + n * IN_F + kg * 8) = lo;
}

// ---------------- Kernel 1: g partials via split-bf16 MFMA -----------------
// grid (M/64, N/64, KSPLIT), 256 thr = 4 waves. Wave = 16 rows x 64 cols.
// C = Ahi*Bhi + Ahi*Blo + Alo*Bhi  (fp32 accum; lo*lo dropped, ~2^-18)
__global__ __launch_bounds__(256)
void gemm_mfma_kernel(const short* __restrict__ Ahi, const short* __restrict__ Alo,
                      const short* __restrict__ Bhi, const short* __restrict__ Blo,
                      float* __restrict__ gp) {
  const int m0 = blockIdx.x * 64;
  const int n0 = blockIdx.y * 64;
  const int kb = blockIdx.z * (IN_F / KSPLIT);
  const int tid = threadIdx.x;
  const int w = tid >> 6, l = tid & 63;
  const int il = l & 15, q = l >> 4;
  const int row = m0 + 16 * w + il;

  const short* ah = Ahi + row * IN_F + kb;
  const short* al = Alo + row * IN_F + kb;
  const short* bh = Bhi + (n0 + il) * IN_F + kb;
  const short* bl = Blo + (n0 + il) * IN_F + kb;

  f32x4 acc[4];
  #pragma unroll
  for (int c = 0; c < 4; ++c) acc[c] = (f32x4){0.f, 0.f, 0.f, 0.f};

  #pragma unroll 2
  for (int k0 = 0; k0 < IN_F / KSPLIT; k0 += 32) {
    const short8 a_h = *(const short8*)(ah + k0 + 8 * q);
    const short8 a_l = *(const short8*)(al + k0 + 8 * q);
    #pragma unroll
    for (int c = 0; c < 4; ++c) {
      const short8 b_h = *(const short8*)(bh + c * 16 * IN_F + k0 + 8 * q);
      const short8 b_l = *(const short8*)(bl + c * 16 * IN_F + k0 + 8 * q);
      acc[c] = __builtin_amdgcn_mfma_f32_16x16x32_bf16(a_h, b_h, acc[c], 0, 0, 0);
      acc[c] = __builtin_amdgcn_mfma_f32_16x16x32_bf16(a_h, b_l, acc[c], 0, 0, 0);
      acc[c] = __builtin_amdgcn_mfma_f32_16x16x32_bf16(a_l, b_h, acc[c], 0, 0, 0);
    }
  }

  float* op = gp + blockIdx.z * (N_NODES * OUTF);
  #pragma unroll
  for (int c = 0; c < 4; ++c)
    #pragma unroll
    for (int r = 0; r < 4; ++r)
      op[(m0 + 16 * w + 4 * q + r) * OUTF + n0 + 16 * c + il] = acc[c][r];
}

// ---------------- Kernel 2: pack adj into bitmask [2048][64] u32 -----------
__global__ __launch_bounds__(256)
void pack_bits_kernel(const int* __restrict__ adj, unsigned* __restrict__ bits) {
  const int idx = blockIdx.x * 256 + threadIdx.x;   // row*64 + word
  const int4* p = (const int4*)(adj + (idx >> 6) * N_NODES + (idx & 63) * 32);
  unsigned w = 0;
  #pragma unroll
  for (int v = 0; v < 8; ++v) {
    const int4 x = p[v];
    w |= (x.x != 0 ? 1u : 0u) << (4 * v + 0);
    w |= (x.y != 0 ? 1u : 0u) << (4 * v + 1);
    w |= (x.z != 0 ? 1u : 0u) << (4 * v + 2);
    w |= (x.w != 0 ? 1u : 0u) << (4 * v + 3);
  }
  bits[idx] = w;
}

// ---------------- Kernel 3: sum K-partials -> s_l, s_r_t, gt(bf16,T) -------
// block: 64 i-rows x 1 head. gt layout: [h][f][node] bf16 (j-contiguous).
__global__ __launch_bounds__(256)
void finish_g_kernel(const float* __restrict__ gp, const float* __restrict__ a,
                     short* __restrict__ gt, float* __restrict__ s_l,
                     float* __restrict__ s_r_t) {
  __shared__ float tile[64][36];   // stride 36: float4-aligned rows
  const int i0 = blockIdx.x * 64;
  const int h  = blockIdx.y;
  const int t  = threadIdx.x;
  {
    const int i = t & 63, fg = t >> 6;   // fg*8 .. fg*8+7
    const int base = (i0 + i) * OUTF + h * HF + fg * 8;
    float4 v0 = *(const float4*)(gp + base);
    float4 v1 = *(const float4*)(gp + base + 4);
    #pragma unroll
    for (int s = 1; s < KSPLIT; ++s) {
      const float4 u0 = *(const float4*)(gp + s * (N_NODES * OUTF) + base);
      const float4 u1 = *(const float4*)(gp + s * (N_NODES * OUTF) + base + 4);
      v0.x += u0.x; v0.y += u0.y; v0.z += u0.z; v0.w += u0.w;
      v1.x += u1.x; v1.y += u1.y; v1.z += u1.z; v1.w += u1.w;
    }
    *(float4*)&tile[i][fg * 8] = v0;
    *(float4*)&tile[i][fg * 8 + 4] = v1;
  }
  __syncthreads();
  if (t < 64) {
    float sl = 0.f, sr = 0.f;
    #pragma unroll
    for (int f = 0; f < HF; ++f) {
      const float gv = tile[t][f];
      sl = fmaf(gv, a[f], sl);
      sr = fmaf(gv, a[HF + f], sr);
    }
    s_l[(i0 + t) * NH + h] = sl;
    s_r_t[h * N_NODES + i0 + t] = sr;
  }
  {
    const int f = t & 31, ig = t >> 5;   // ig = 0..7
    short8 o;
    #pragma unroll
    for (int rr = 0; rr < 8; ++rr) o[rr] = f2bf(tile[8 * ig + rr][f]);
    *(short8*)(gt + (h * HF + f) * N_NODES + i0 + 8 * ig) = o;
  }
}

// ---------------- Kernel 4: MFMA attention partials (no LDS, no barriers) --
// grid (128 i-tiles, JSPLIT). 8 waves/block, wave = head. 16 i x 32 f per wave.
__global__ __launch_bounds__(512)
void attn_mfma_kernel(const unsigned* __restrict__ bits, const short* __restrict__ gt,
                      const float* __restrict__ s_l, const float* __restrict__ s_r_t,
                      float* __restrict__ pout, float* __restrict__ pl) {
  const int i0    = blockIdx.x * 16;
  const int split = blockIdx.y;
  const int tid   = threadIdx.x;
  const int h = tid >> 6;
  const int l = tid & 63;
  const int il = l & 15;        // A row / D col
  const int q  = l >> 4;        // k-group: k = 8q + r

  const float slv = s_l[(i0 + il) * NH + h];
  const unsigned* bitrow = bits + (i0 + il) * 64;
  const float* srh = s_r_t + h * N_NODES;
  const short* g0p = gt + (h * HF + il) * N_NODES;
  const short* g1p = gt + (h * HF + 16 + il) * N_NODES;

  f32x4 acc0 = {0.f, 0.f, 0.f, 0.f};
  f32x4 acc1 = {0.f, 0.f, 0.f, 0.f};
  float denom = 0.f;

  const int jbase = split * JR;
  for (int j0 = jbase; j0 < jbase + JR; j0 += 32) {
    const unsigned word = bitrow[j0 >> 5];
    const float4 sra = *(const float4*)(srh + j0 + 8 * q);
    const float4 srb = *(const float4*)(srh + j0 + 8 * q + 4);
    const float sr_[8] = {sra.x, sra.y, sra.z, sra.w, srb.x, srb.y, srb.z, srb.w};
    short8 afrag;
    #pragma unroll
    for (int r = 0; r < 8; ++r) {
      float e = slv + sr_[r];
      e = fmaxf(e, 0.2f * e);                                 // leaky relu
      const float wv = ((word >> (8 * q + r)) & 1u) ? __expf(e) : 0.f;
      const short wb = f2bf(wv);
      afrag[r] = wb;
      denom += bf2f(wb);    // denom consistent with bf16 numerator
    }
    const short8 b0 = *(const short8*)(g0p + j0 + 8 * q);
    const short8 b1 = *(const short8*)(g1p + j0 + 8 * q);
    acc0 = __builtin_amdgcn_mfma_f32_16x16x32_bf16(afrag, b0, acc0, 0, 0, 0);
    acc1 = __builtin_amdgcn_mfma_f32_16x16x32_bf16(afrag, b1, acc1, 0, 0, 0);
  }

  denom += __shfl_xor(denom, 16, 64);
  denom += __shfl_xor(denom, 32, 64);

  float* pb = pout + split * (N_NODES * OUTF);
  #pragma unroll
  for (int r = 0; r < 4; ++r) {
    const int irow = i0 + 4 * q + r;      // D: row = 4*(l>>4)+r, col = l&15
    pb[irow * OUTF + h * HF + il]      = acc0[r];
    pb[irow * OUTF + h * HF + 16 + il] = acc1[r];
  }
  if (q == 0) pl[split * (N_NODES * NH) + (i0 + il) * NH + h] = denom;
}

// ---------------- Kernel 5: sum partials, normalize ------------------------
__global__ __launch_bounds__(256)
void reduce_kernel(const float* __restrict__ pout, const float* __restrict__ pl,
                   float* __restrict__ out) {
  const int idx = blockIdx.x * 256 + threadIdx.x;  // over N_NODES*OUTF
  float s = 0.f;
  #pragma unroll
  for (int p = 0; p < JSPLIT; ++p) s += pout[p * (N_NODES * OUTF) + idx];
  const int ih = idx >> 5;  // i*8 + h
  float lsum = 0.f;
  #pragma unroll
  for (int p = 0; p < JSPLIT; ++p) lsum += pl[p * (N_NODES * NH) + ih];
  out[idx] = s / lsum;
}

// ---------------------------------------------------------------------------
extern "C" void kernel_launch(void* const* d_in, const int* in_sizes, int n_in,
                              void* d_out, int out_size, void* d_ws, size_t ws_size,
                              hipStream_t stream) {
  const float* h   = (const float*)d_in[0];
  const int*   adj = (const int*)d_in[1];
  const float* W   = (const float*)d_in[2];
  const float* a   = (const float*)d_in[3];
  float* out = (float*)d_out;

  float* gp    = (float*)d_ws;                       // KSPLIT * 2048*256 (aliased w/ pout)
  float* pout  = gp;                                 // attn partials reuse gp
  float* s_l   = gp + KSPLIT * N_NODES * OUTF;       // 2048*8
  float* s_r_t = s_l + N_NODES * NH;                 // 8*2048
  float* pl    = s_r_t + NH * N_NODES;               // JSPLIT * 2048*8
  unsigned* bits = (unsigned*)(pl + JSPLIT * N_NODES * NH);   // 2048*64 u32
  short* gt    = (short*)(bits + N_NODES * 64);      // 8*32*2048 bf16
  short* h_hi  = gt + NH * HF * N_NODES;             // 2048*1024
  short* h_lo  = h_hi + N_NODES * IN_F;              // 2048*1024
  short* wt_hi = h_lo + N_NODES * IN_F;              // 256*1024
  short* wt_lo = wt_hi + OUTF * IN_F;                // 256*1024

  prep_h_kernel<<<(N_NODES * IN_F / 8) / 256, 256, 0, stream>>>(h, h_hi, h_lo);
  prep_w_kernel<<<(OUTF * IN_F / 8) / 256, 256, 0, stream>>>(W, wt_hi, wt_lo);
  pack_bits_kernel<<<(N_NODES * 64) / 256, 256, 0, stream>>>(adj, bits);
  gemm_mfma_kernel<<<dim3(N_NODES / 64, OUTF / 64, KSPLIT), 256, 0, stream>>>(
      h_hi, h_lo, wt_hi, wt_lo, gp);
  finish_g_kernel<<<dim3(N_NODES / 64, NH), 256, 0, stream>>>(gp, a, gt, s_l, s_r_t);
  attn_mfma_kernel<<<dim3(N_NODES / 16, JSPLIT), 512, 0, stream>>>(bits, gt, s_l, s_r_t, pout, pl);
  reduce_kernel<<<(N_NODES * OUTF) / 256, 256, 0, stream>>>(pout, pl, out);
}